// Round 4
// 885.917 us; speedup vs baseline: 1.0126x; 1.0126x over previous
//
#include <hip/hip_runtime.h>
#include <hip/hip_bf16.h>

#define ALPHA 0.2f
#define NEGV  -9000000000000000.0f

typedef __attribute__((ext_vector_type(8))) short bf16x8;
typedef __attribute__((ext_vector_type(4))) float f32x4;

// fp32 -> bf16 (RNE) bit trick; inputs are finite so no NaN care needed.
__device__ __forceinline__ short f2b(float f) {
  unsigned u = __float_as_uint(f);
  unsigned r = (u + 0x7FFFu + ((u >> 16) & 1u)) >> 16;
  return (short)r;
}

// ---------------- Kernel 1: Whp[kc][h,b,n,o] = partial sum_i x[b,n,i] * W[h,b,i,o] ----------------
// Also folds the a1/a2 dot products (k2's reduction phase) into the epilogue:
// dp[kc][hb][0..13] = partial Wh·a1, dp[kc][hb][14..27] = partial Wh·a2.
// grid 512 = (h*32+b)*4 + kchunk ; 256 threads. Main loop is explicitly double-buffered
// (prefetch rows ii+4..ii+7 while FMA-ing rows ii..ii+3) so the W stream never drains.
__global__ __launch_bounds__(256) void k1_wh(const float* __restrict__ x,
                                             const float* __restrict__ W,
                                             const float* __restrict__ a,
                                             float* __restrict__ Whp,
                                             float* __restrict__ dp) {
  int blk = blockIdx.x;
  int kc = blk & 3;
  int hb = blk >> 2;          // h*32+b
  int b  = hb & 31;
  int t  = threadIdx.x;
  __shared__ float xs[14][256];
  __shared__ float red[4][28];
  int i0 = kc * 256;
  const float* xb = x + (size_t)b * 14336 + i0;
  #pragma unroll
  for (int n = 0; n < 14; ++n) xs[n][t] = xb[n * 1024 + t];
  __syncthreads();

  const float* Wp = W + ((size_t)hb * 1024 + i0) * 1024 + 4 * t;   // o = 4t..4t+3
  float4 acc[14];
  #pragma unroll
  for (int n = 0; n < 14; ++n) acc[n] = make_float4(0.f, 0.f, 0.f, 0.f);

  float4 w0 = *(const float4*)(Wp);
  float4 w1 = *(const float4*)(Wp + 1024);
  float4 w2 = *(const float4*)(Wp + 2048);
  float4 w3 = *(const float4*)(Wp + 3072);
  for (int ii = 0; ii < 256; ii += 8) {
    int j1 = (ii + 4) & 255;                       // wrap keeps last prefetch in-bounds (dead value)
    float4 n0 = *(const float4*)(Wp + (size_t)(j1    ) * 1024);
    float4 n1 = *(const float4*)(Wp + (size_t)(j1 + 1) * 1024);
    float4 n2 = *(const float4*)(Wp + (size_t)(j1 + 2) * 1024);
    float4 n3 = *(const float4*)(Wp + (size_t)(j1 + 3) * 1024);
    #pragma unroll
    for (int n = 0; n < 14; ++n) {
      float4 xn = *(const float4*)&xs[n][ii];      // wave-uniform -> LDS broadcast
      acc[n].x += xn.x * w0.x + xn.y * w1.x + xn.z * w2.x + xn.w * w3.x;
      acc[n].y += xn.x * w0.y + xn.y * w1.y + xn.z * w2.y + xn.w * w3.y;
      acc[n].z += xn.x * w0.z + xn.y * w1.z + xn.z * w2.z + xn.w * w3.z;
      acc[n].w += xn.x * w0.w + xn.y * w1.w + xn.z * w2.w + xn.w * w3.w;
    }
    int j2 = (ii + 8) & 255;
    w0 = *(const float4*)(Wp + (size_t)(j2    ) * 1024);
    w1 = *(const float4*)(Wp + (size_t)(j2 + 1) * 1024);
    w2 = *(const float4*)(Wp + (size_t)(j2 + 2) * 1024);
    w3 = *(const float4*)(Wp + (size_t)(j2 + 3) * 1024);
    #pragma unroll
    for (int n = 0; n < 14; ++n) {
      float4 xn = *(const float4*)&xs[n][ii + 4];
      acc[n].x += xn.x * n0.x + xn.y * n1.x + xn.z * n2.x + xn.w * n3.x;
      acc[n].y += xn.x * n0.y + xn.y * n1.y + xn.z * n2.y + xn.w * n3.y;
      acc[n].z += xn.x * n0.z + xn.y * n1.z + xn.z * n2.z + xn.w * n3.z;
      acc[n].w += xn.x * n0.w + xn.y * n1.w + xn.z * n2.w + xn.w * n3.w;
    }
  }

  float* dst = Whp + (size_t)kc * 1835008 + (size_t)hb * 14336 + 4 * t;
  #pragma unroll
  for (int n = 0; n < 14; ++n) *(float4*)(dst + n * 1024) = acc[n];

  // fold in Wh·a1 / Wh·a2 partial dots (replaces kernel 2's reduction phase)
  const float* ap = a + (size_t)hb * 2048 + 4 * t;
  float4 a1v = *(const float4*)ap;
  float4 a2v = *(const float4*)(ap + 1024);
  int lane = t & 63, w = t >> 6;
  #pragma unroll
  for (int n = 0; n < 14; ++n) {
    float p1 = acc[n].x * a1v.x + acc[n].y * a1v.y + acc[n].z * a1v.z + acc[n].w * a1v.w;
    float p2 = acc[n].x * a2v.x + acc[n].y * a2v.y + acc[n].z * a2v.z + acc[n].w * a2v.w;
    #pragma unroll
    for (int s = 32; s >= 1; s >>= 1) {
      p1 += __shfl_xor(p1, s);
      p2 += __shfl_xor(p2, s);
    }
    if (lane == 0) { red[w][n] = p1; red[w][14 + n] = p2; }
  }
  __syncthreads();
  if (t < 28) {
    dp[((size_t)kc * 128 + hb) * 28 + t] =
        red[0][t] + red[1][t] + red[2][t] + red[3][t];
  }
}

// ---------------- Kernel 3 (fused att + h_prime): ----------------
// Prologue: sum dp partials -> wh1s/wh2s, compute 14x14 softmax att in LDS (never hits global).
// Main: hp[h,b,n,o] = sum_m att[n,m] * (sum_kc Whp[kc][h,b,m,o])  (Whp partial-sum inline, L3 hits).
// grid 256 = (h*32+b)*2 + ochunk ; 128 threads, each owns 4 o.
__global__ __launch_bounds__(128) void k3_atthp(const float* __restrict__ Whp,
                                                const float* __restrict__ dp,
                                                const float* __restrict__ adj,
                                                float* __restrict__ hp) {
  int blk = blockIdx.x;
  int hb = blk >> 1, oc = blk & 1;
  int b  = hb & 31;
  int t  = threadIdx.x;
  __shared__ float wh1s[14], wh2s[14], att_s[196];
  if (t < 28) {
    const float* d = dp + (size_t)hb * 28 + t;
    float v = d[0] + d[3584] + d[7168] + d[10752];   // kc stride = 128*28
    if (t < 14) wh1s[t] = v; else wh2s[t - 14] = v;
  }
  __syncthreads();
  if (t < 14) {
    int m = t;
    const float* adjb = adj + b * 196;
    float col[14];
    float mx = -1e30f;
    #pragma unroll
    for (int n = 0; n < 14; ++n) {
      float e = wh1s[n] + wh2s[m];
      e = (e > 0.f) ? e : ALPHA * e;
      e = (adjb[n * 14 + m] > 0.f) ? e : NEGV;
      col[n] = e;
      mx = fmaxf(mx, e);
    }
    float s = 0.f;
    #pragma unroll
    for (int n = 0; n < 14; ++n) { col[n] = expf(col[n] - mx); s += col[n]; }
    float inv = 1.f / s;
    #pragma unroll
    for (int n = 0; n < 14; ++n) att_s[n * 14 + m] = col[n] * inv;
  }
  __syncthreads();

  int o4 = oc * 512 + 4 * t;
  const float* wp0 = Whp + (size_t)hb * 14336 + o4;
  const size_t S = 1835008;
  float4 acc[14];
  #pragma unroll
  for (int n = 0; n < 14; ++n) acc[n] = make_float4(0.f, 0.f, 0.f, 0.f);
  #pragma unroll
  for (int m = 0; m < 14; ++m) {
    const float* q = wp0 + (size_t)m * 1024;
    float4 v0 = *(const float4*)(q);
    float4 v1 = *(const float4*)(q + S);
    float4 v2 = *(const float4*)(q + 2 * S);
    float4 v3 = *(const float4*)(q + 3 * S);
    float4 wm = make_float4(v0.x + v1.x + v2.x + v3.x,
                            v0.y + v1.y + v2.y + v3.y,
                            v0.z + v1.z + v2.z + v3.z,
                            v0.w + v1.w + v2.w + v3.w);
    #pragma unroll
    for (int n = 0; n < 14; ++n) {
      float anm = att_s[n * 14 + m];   // wave-uniform -> broadcast
      acc[n].x += anm * wm.x;
      acc[n].y += anm * wm.y;
      acc[n].z += anm * wm.z;
      acc[n].w += anm * wm.w;
    }
  }
  float* dsto = hp + (size_t)hb * 14336 + o4;
  #pragma unroll
  for (int n = 0; n < 14; ++n) *(float4*)(dsto + n * 1024) = acc[n];
}

// ---------------- Kernel 4: fc via bf16 MFMA into per-(kc,h) partial tiles (no atomics) ----------------
// grid 512 = kc(8) | oc(16) | h(4) ; 256 threads (4 waves). Block tile 32b x 64o, K_T=256.
// LDS rows padded to 272 bf16 (544 B) so frag reads land ~2-way on banks (free).
__global__ __launch_bounds__(256) void k4_fc(const float* __restrict__ hp,
                                             const float* __restrict__ fcw,
                                             float* __restrict__ oaccp) {
  int blk = blockIdx.x;
  int kc = blk & 7;
  int oc = (blk >> 3) & 15;
  int h  = blk >> 7;
  int t = threadIdx.x;
  int lane = t & 63, w = t >> 6;
  int mw = w & 1, nw = w >> 1;
  __shared__ __align__(16) short As[32][272];
  __shared__ __align__(16) short Bs[64][272];
  const int o0 = oc * 64;
  const size_t hpb = (size_t)h * 32 * 14336;
  const size_t fwb = (size_t)h * 1024 * 14336;
  f32x4 c0 = {0.f, 0.f, 0.f, 0.f};
  f32x4 c1 = {0.f, 0.f, 0.f, 0.f};

  for (int tt = 0; tt < 7; ++tt) {
    int f0 = kc * 1792 + tt * 256;
    // stage A (32 x 256 fp32 -> bf16)
    #pragma unroll
    for (int p = 0; p < 8; ++p) {
      int f4 = p * 256 + t;
      int row = f4 >> 6, c4 = f4 & 63;
      float4 wv = *(const float4*)(hp + hpb + (size_t)row * 14336 + f0 + 4 * c4);
      short4 s4 = make_short4(f2b(wv.x), f2b(wv.y), f2b(wv.z), f2b(wv.w));
      *(short4*)&As[row][4 * c4] = s4;
    }
    // stage B (64 x 256 fp32 -> bf16); fcw is [o][f] i.e. already B^T (n-major, k-contiguous)
    #pragma unroll
    for (int p = 0; p < 16; ++p) {
      int f4 = p * 256 + t;
      int row = f4 >> 6, c4 = f4 & 63;
      float4 wv = *(const float4*)(fcw + fwb + (size_t)(o0 + row) * 14336 + f0 + 4 * c4);
      short4 s4 = make_short4(f2b(wv.x), f2b(wv.y), f2b(wv.z), f2b(wv.w));
      *(short4*)&Bs[row][4 * c4] = s4;
    }
    __syncthreads();
    #pragma unroll
    for (int ks = 0; ks < 8; ++ks) {
      bf16x8 af = *(const bf16x8*)&As[mw * 16 + (lane & 15)][ks * 32 + (lane >> 4) * 8];
      bf16x8 b0 = *(const bf16x8*)&Bs[nw * 32 + (lane & 15)][ks * 32 + (lane >> 4) * 8];
      bf16x8 b1 = *(const bf16x8*)&Bs[nw * 32 + 16 + (lane & 15)][ks * 32 + (lane >> 4) * 8];
      c0 = __builtin_amdgcn_mfma_f32_16x16x32_bf16(af, b0, c0, 0, 0, 0);
      c1 = __builtin_amdgcn_mfma_f32_16x16x32_bf16(af, b1, c1, 0, 0, 0);
    }
    __syncthreads();
  }
  // C/D layout: col = lane&15, row = (lane>>4)*4 + reg  [m89-verified]
  float* op = oaccp + (size_t)(kc * 4 + h) * 32768;   // [kc,h][b=32][o=1024]
  int br   = mw * 16 + (lane >> 4) * 4;
  int ocol = o0 + nw * 32 + (lane & 15);
  #pragma unroll
  for (int r = 0; r < 4; ++r) {
    op[(br + r) * 1024 + ocol]      = c0[r];
    op[(br + r) * 1024 + ocol + 16] = c1[r];
  }
}

// ---------------- Kernel 5: out[b,o] = log_softmax(sum_p oaccp[p][b,:] + sum_h fc_b[h,:]) ----------------
// float4 throughout; 32 blocks x 256 threads, thread owns o = 4t..4t+3.
__global__ __launch_bounds__(256) void k5_lsm(const float* __restrict__ oaccp,
                                              const float* __restrict__ fcb,
                                              float* __restrict__ out) {
  int b = blockIdx.x, t = threadIdx.x;
  int lane = t & 63, wid = t >> 6;
  __shared__ float redm[4], reds[4];
  float4 f0 = *(const float4*)(fcb + 4 * t);
  float4 f1 = *(const float4*)(fcb + 1024 + 4 * t);
  float4 f2 = *(const float4*)(fcb + 2048 + 4 * t);
  float4 f3 = *(const float4*)(fcb + 3072 + 4 * t);
  float4 v = make_float4(f0.x + f1.x + f2.x + f3.x,
                         f0.y + f1.y + f2.y + f3.y,
                         f0.z + f1.z + f2.z + f3.z,
                         f0.w + f1.w + f2.w + f3.w);
  #pragma unroll
  for (int p = 0; p < 32; ++p) {
    float4 o = *(const float4*)(oaccp + (size_t)p * 32768 + b * 1024 + 4 * t);
    v.x += o.x; v.y += o.y; v.z += o.z; v.w += o.w;
  }
  float mx = fmaxf(fmaxf(v.x, v.y), fmaxf(v.z, v.w));
  #pragma unroll
  for (int s = 32; s >= 1; s >>= 1) mx = fmaxf(mx, __shfl_xor(mx, s));
  if (lane == 0) redm[wid] = mx;
  __syncthreads();
  mx = fmaxf(fmaxf(redm[0], redm[1]), fmaxf(redm[2], redm[3]));
  float sm = expf(v.x - mx) + expf(v.y - mx) + expf(v.z - mx) + expf(v.w - mx);
  #pragma unroll
  for (int s = 32; s >= 1; s >>= 1) sm += __shfl_xor(sm, s);
  if (lane == 0) reds[wid] = sm;
  __syncthreads();
  sm = reds[0] + reds[1] + reds[2] + reds[3];
  float lse = mx + logf(sm);
  float4 r = make_float4(v.x - lse, v.y - lse, v.z - lse, v.w - lse);
  *(float4*)(out + b * 1024 + 4 * t) = r;
}

extern "C" void kernel_launch(void* const* d_in, const int* in_sizes, int n_in,
                              void* d_out, int out_size, void* d_ws, size_t ws_size,
                              hipStream_t stream) {
  const float* x   = (const float*)d_in[0];
  const float* adj = (const float*)d_in[1];
  const float* W   = (const float*)d_in[2];
  const float* a   = (const float*)d_in[3];
  const float* fcw = (const float*)d_in[4];
  const float* fcb = (const float*)d_in[5];
  float* out = (float*)d_out;

  char* ws = (char*)d_ws;
  float* Whp = (float*)(ws);                // 4 * 7,340,032 = 29,360,128 B
  float* dp  = (float*)(ws + 29360128);     // 4*128*28*4 = 57,344 B
  float* hp  = (float*)(ws + 29417472);     // 7,340,032 B
  float* oap = (float*)(ws + 36757504);     // 32 * 32 * 1024 * 4 = 4,194,304 B

  k1_wh<<<512, 256, 0, stream>>>(x, W, a, Whp, dp);
  k3_atthp<<<256, 128, 0, stream>>>(Whp, dp, adj, hp);
  k4_fc<<<512, 256, 0, stream>>>(hp, fcw, oap);
  k5_lsm<<<32, 256, 0, stream>>>(oap, fcb, out);
}

// Round 5
// 861.552 us; speedup vs baseline: 1.0413x; 1.0283x over previous
//
#include <hip/hip_runtime.h>
#include <hip/hip_bf16.h>

#define ALPHA 0.2f
#define NEGV  -9000000000000000.0f

typedef __attribute__((ext_vector_type(8))) short bf16x8;
typedef __attribute__((ext_vector_type(4))) float f32x4;

// fp32 -> bf16 (RNE) bit trick; inputs are finite so no NaN care needed.
__device__ __forceinline__ short f2b(float f) {
  unsigned u = __float_as_uint(f);
  unsigned r = (u + 0x7FFFu + ((u >> 16) & 1u)) >> 16;
  return (short)r;
}

// ---------------- Kernel 1: Whp[kc][h,b,n,o] = partial sum_i x[b,n,i] * W[h,b,i,o] ----------------
// Epilogue folds the a1/a2 dots: dp[kc][hb][0..13] = partial Wh·a1, [14..27] = partial Wh·a2.
// grid 512 = (h*32+b)*4 + kchunk ; 256 threads. BW-saturated (round-4 evidence) — unchanged.
__global__ __launch_bounds__(256) void k1_wh(const float* __restrict__ x,
                                             const float* __restrict__ W,
                                             const float* __restrict__ a,
                                             float* __restrict__ Whp,
                                             float* __restrict__ dp) {
  int blk = blockIdx.x;
  int kc = blk & 3;
  int hb = blk >> 2;          // h*32+b
  int b  = hb & 31;
  int t  = threadIdx.x;
  __shared__ float xs[14][256];
  __shared__ float red[4][28];
  int i0 = kc * 256;
  const float* xb = x + (size_t)b * 14336 + i0;
  #pragma unroll
  for (int n = 0; n < 14; ++n) xs[n][t] = xb[n * 1024 + t];
  __syncthreads();

  const float* Wp = W + ((size_t)hb * 1024 + i0) * 1024 + 4 * t;   // o = 4t..4t+3
  float4 acc[14];
  #pragma unroll
  for (int n = 0; n < 14; ++n) acc[n] = make_float4(0.f, 0.f, 0.f, 0.f);

  float4 w0 = *(const float4*)(Wp);
  float4 w1 = *(const float4*)(Wp + 1024);
  float4 w2 = *(const float4*)(Wp + 2048);
  float4 w3 = *(const float4*)(Wp + 3072);
  for (int ii = 0; ii < 256; ii += 8) {
    int j1 = (ii + 4) & 255;                       // wrap keeps last prefetch in-bounds (dead value)
    float4 n0 = *(const float4*)(Wp + (size_t)(j1    ) * 1024);
    float4 n1 = *(const float4*)(Wp + (size_t)(j1 + 1) * 1024);
    float4 n2 = *(const float4*)(Wp + (size_t)(j1 + 2) * 1024);
    float4 n3 = *(const float4*)(Wp + (size_t)(j1 + 3) * 1024);
    #pragma unroll
    for (int n = 0; n < 14; ++n) {
      float4 xn = *(const float4*)&xs[n][ii];      // wave-uniform -> LDS broadcast
      acc[n].x += xn.x * w0.x + xn.y * w1.x + xn.z * w2.x + xn.w * w3.x;
      acc[n].y += xn.x * w0.y + xn.y * w1.y + xn.z * w2.y + xn.w * w3.y;
      acc[n].z += xn.x * w0.z + xn.y * w1.z + xn.z * w2.z + xn.w * w3.z;
      acc[n].w += xn.x * w0.w + xn.y * w1.w + xn.z * w2.w + xn.w * w3.w;
    }
    int j2 = (ii + 8) & 255;
    w0 = *(const float4*)(Wp + (size_t)(j2    ) * 1024);
    w1 = *(const float4*)(Wp + (size_t)(j2 + 1) * 1024);
    w2 = *(const float4*)(Wp + (size_t)(j2 + 2) * 1024);
    w3 = *(const float4*)(Wp + (size_t)(j2 + 3) * 1024);
    #pragma unroll
    for (int n = 0; n < 14; ++n) {
      float4 xn = *(const float4*)&xs[n][ii + 4];
      acc[n].x += xn.x * n0.x + xn.y * n1.x + xn.z * n2.x + xn.w * n3.x;
      acc[n].y += xn.x * n0.y + xn.y * n1.y + xn.z * n2.y + xn.w * n3.y;
      acc[n].z += xn.x * n0.z + xn.y * n1.z + xn.z * n2.z + xn.w * n3.z;
      acc[n].w += xn.x * n0.w + xn.y * n1.w + xn.z * n2.w + xn.w * n3.w;
    }
  }

  float* dst = Whp + (size_t)kc * 1835008 + (size_t)hb * 14336 + 4 * t;
  #pragma unroll
  for (int n = 0; n < 14; ++n) *(float4*)(dst + n * 1024) = acc[n];

  // fold in Wh·a1 / Wh·a2 partial dots
  const float* ap = a + (size_t)hb * 2048 + 4 * t;
  float4 a1v = *(const float4*)ap;
  float4 a2v = *(const float4*)(ap + 1024);
  int lane = t & 63, w = t >> 6;
  #pragma unroll
  for (int n = 0; n < 14; ++n) {
    float p1 = acc[n].x * a1v.x + acc[n].y * a1v.y + acc[n].z * a1v.z + acc[n].w * a1v.w;
    float p2 = acc[n].x * a2v.x + acc[n].y * a2v.y + acc[n].z * a2v.z + acc[n].w * a2v.w;
    #pragma unroll
    for (int s = 32; s >= 1; s >>= 1) {
      p1 += __shfl_xor(p1, s);
      p2 += __shfl_xor(p2, s);
    }
    if (lane == 0) { red[w][n] = p1; red[w][14 + n] = p2; }
  }
  __syncthreads();
  if (t < 28) {
    dp[((size_t)kc * 128 + hb) * 28 + t] =
        red[0][t] + red[1][t] + red[2][t] + red[3][t];
  }
}

// ---------------- Kernel 3 (fused att + h_prime), latency-hiding split ----------------
// grid 512 = hb(128) x nh(2) x oc(2); 128 threads. Block computes hp[h,b, n in 7-range, o in 512-range].
// Per-block work halved vs round-4 (2 blocks/CU instead of 1) to hide the L2/L3 load latency.
__global__ __launch_bounds__(128) void k3_atthp(const float* __restrict__ Whp,
                                                const float* __restrict__ dp,
                                                const float* __restrict__ adj,
                                                float* __restrict__ hp) {
  int blk = blockIdx.x;
  int hb = blk >> 2;
  int nh = (blk >> 1) & 1;
  int oc = blk & 1;
  int b  = hb & 31;
  int t  = threadIdx.x;
  __shared__ float wh1s[14], wh2s[14], att_s[196];
  if (t < 28) {
    const float* d = dp + (size_t)hb * 28 + t;
    float v = d[0] + d[3584] + d[7168] + d[10752];   // kc stride = 128*28
    if (t < 14) wh1s[t] = v; else wh2s[t - 14] = v;
  }
  __syncthreads();
  if (t < 14) {
    int m = t;
    const float* adjb = adj + b * 196;
    float col[14];
    float mx = -1e30f;
    #pragma unroll
    for (int n = 0; n < 14; ++n) {
      float e = wh1s[n] + wh2s[m];
      e = (e > 0.f) ? e : ALPHA * e;
      e = (adjb[n * 14 + m] > 0.f) ? e : NEGV;
      col[n] = e;
      mx = fmaxf(mx, e);
    }
    float s = 0.f;
    #pragma unroll
    for (int n = 0; n < 14; ++n) { col[n] = expf(col[n] - mx); s += col[n]; }
    float inv = 1.f / s;
    #pragma unroll
    for (int n = 0; n < 14; ++n) att_s[n * 14 + m] = col[n] * inv;
  }
  __syncthreads();

  int o4 = oc * 512 + 4 * t;          // t<128 -> covers 512 o
  int n0 = nh * 7;
  const float* wp0 = Whp + (size_t)hb * 14336 + o4;
  const size_t S = 1835008;
  float4 acc[7];
  #pragma unroll
  for (int j = 0; j < 7; ++j) acc[j] = make_float4(0.f, 0.f, 0.f, 0.f);
  #pragma unroll
  for (int m = 0; m < 14; ++m) {
    const float* q = wp0 + (size_t)m * 1024;
    float4 v0 = *(const float4*)(q);
    float4 v1 = *(const float4*)(q + S);
    float4 v2 = *(const float4*)(q + 2 * S);
    float4 v3 = *(const float4*)(q + 3 * S);
    float4 wm = make_float4(v0.x + v1.x + v2.x + v3.x,
                            v0.y + v1.y + v2.y + v3.y,
                            v0.z + v1.z + v2.z + v3.z,
                            v0.w + v1.w + v2.w + v3.w);
    #pragma unroll
    for (int j = 0; j < 7; ++j) {
      float anm = att_s[(n0 + j) * 14 + m];   // wave-uniform -> broadcast
      acc[j].x += anm * wm.x;
      acc[j].y += anm * wm.y;
      acc[j].z += anm * wm.z;
      acc[j].w += anm * wm.w;
    }
  }
  float* dsto = hp + (size_t)hb * 14336 + o4;
  #pragma unroll
  for (int j = 0; j < 7; ++j) *(float4*)(dsto + (n0 + j) * 1024) = acc[j];
}

// ---------------- Kernel 4: fc via bf16 MFMA into per-(kc,h) partial tiles (no atomics) ----------------
// grid 1024 = kc(16) | oc(16) | h(4) ; 256 threads (4 waves), 4 blocks/CU. Tile 32b x 64o, K_T=128.
// LDS row pitch 136 shorts (272 B): frag-read lane stride = 68 dwords -> lane i hits banks
// 4i..4i+3 (mod 32) -> 2 lanes/bank = conflict-free (m136: 2-way is free). Round-4 pitch 272
// was 4-way (1.58x tax) on every ds_read_b128.
__global__ __launch_bounds__(256) void k4_fc(const float* __restrict__ hp,
                                             const float* __restrict__ fcw,
                                             float* __restrict__ oaccp) {
  int blk = blockIdx.x;
  int kc = blk & 15;
  int oc = (blk >> 4) & 15;
  int h  = blk >> 8;
  int t = threadIdx.x;
  int lane = t & 63, w = t >> 6;
  int mw = w & 1, nw = w >> 1;
  __shared__ __align__(16) short As[32][136];
  __shared__ __align__(16) short Bs[64][136];
  const int o0 = oc * 64;
  const size_t hpb = (size_t)h * 32 * 14336;
  const size_t fwb = (size_t)h * 1024 * 14336;
  f32x4 c0 = {0.f, 0.f, 0.f, 0.f};
  f32x4 c1 = {0.f, 0.f, 0.f, 0.f};

  for (int tt = 0; tt < 7; ++tt) {
    int f0 = kc * 896 + tt * 128;
    // stage A (32 x 128 fp32 -> bf16): 4 float4 per thread
    #pragma unroll
    for (int p = 0; p < 4; ++p) {
      int f4 = p * 256 + t;
      int row = f4 >> 5, c4 = f4 & 31;
      float4 wv = *(const float4*)(hp + hpb + (size_t)row * 14336 + f0 + 4 * c4);
      short4 s4 = make_short4(f2b(wv.x), f2b(wv.y), f2b(wv.z), f2b(wv.w));
      *(short4*)&As[row][4 * c4] = s4;
    }
    // stage B (64 x 128 fp32 -> bf16): 8 float4 per thread; fcw is [o][f] = B^T
    #pragma unroll
    for (int p = 0; p < 8; ++p) {
      int f4 = p * 256 + t;
      int row = f4 >> 5, c4 = f4 & 31;
      float4 wv = *(const float4*)(fcw + fwb + (size_t)(o0 + row) * 14336 + f0 + 4 * c4);
      short4 s4 = make_short4(f2b(wv.x), f2b(wv.y), f2b(wv.z), f2b(wv.w));
      *(short4*)&Bs[row][4 * c4] = s4;
    }
    __syncthreads();
    #pragma unroll
    for (int ks = 0; ks < 4; ++ks) {
      bf16x8 af = *(const bf16x8*)&As[mw * 16 + (lane & 15)][ks * 32 + (lane >> 4) * 8];
      bf16x8 b0 = *(const bf16x8*)&Bs[nw * 32 + (lane & 15)][ks * 32 + (lane >> 4) * 8];
      bf16x8 b1 = *(const bf16x8*)&Bs[nw * 32 + 16 + (lane & 15)][ks * 32 + (lane >> 4) * 8];
      c0 = __builtin_amdgcn_mfma_f32_16x16x32_bf16(af, b0, c0, 0, 0, 0);
      c1 = __builtin_amdgcn_mfma_f32_16x16x32_bf16(af, b1, c1, 0, 0, 0);
    }
    __syncthreads();
  }
  // C/D layout: col = lane&15, row = (lane>>4)*4 + reg  [m89-verified]
  float* op = oaccp + (size_t)(kc * 4 + h) * 32768;   // [kc,h][b=32][o=1024]
  int br   = mw * 16 + (lane >> 4) * 4;
  int ocol = o0 + nw * 32 + (lane & 15);
  #pragma unroll
  for (int r = 0; r < 4; ++r) {
    op[(br + r) * 1024 + ocol]      = c0[r];
    op[(br + r) * 1024 + ocol + 16] = c1[r];
  }
}

// ---------------- Kernel 5: out[b,o] = log_softmax(sum_p oaccp[p][b,:] + sum_h fc_b[h,:]) ----------------
// float4 throughout; 32 blocks x 256 threads; now 64 partial buffers (kc=16 x h=4).
__global__ __launch_bounds__(256) void k5_lsm(const float* __restrict__ oaccp,
                                              const float* __restrict__ fcb,
                                              float* __restrict__ out) {
  int b = blockIdx.x, t = threadIdx.x;
  int lane = t & 63, wid = t >> 6;
  __shared__ float redm[4], reds[4];
  float4 f0 = *(const float4*)(fcb + 4 * t);
  float4 f1 = *(const float4*)(fcb + 1024 + 4 * t);
  float4 f2 = *(const float4*)(fcb + 2048 + 4 * t);
  float4 f3 = *(const float4*)(fcb + 3072 + 4 * t);
  float4 v = make_float4(f0.x + f1.x + f2.x + f3.x,
                         f0.y + f1.y + f2.y + f3.y,
                         f0.z + f1.z + f2.z + f3.z,
                         f0.w + f1.w + f2.w + f3.w);
  #pragma unroll
  for (int p = 0; p < 64; ++p) {
    float4 o = *(const float4*)(oaccp + (size_t)p * 32768 + b * 1024 + 4 * t);
    v.x += o.x; v.y += o.y; v.z += o.z; v.w += o.w;
  }
  float mx = fmaxf(fmaxf(v.x, v.y), fmaxf(v.z, v.w));
  #pragma unroll
  for (int s = 32; s >= 1; s >>= 1) mx = fmaxf(mx, __shfl_xor(mx, s));
  if (lane == 0) redm[wid] = mx;
  __syncthreads();
  mx = fmaxf(fmaxf(redm[0], redm[1]), fmaxf(redm[2], redm[3]));
  float sm = expf(v.x - mx) + expf(v.y - mx) + expf(v.z - mx) + expf(v.w - mx);
  #pragma unroll
  for (int s = 32; s >= 1; s >>= 1) sm += __shfl_xor(sm, s);
  if (lane == 0) reds[wid] = sm;
  __syncthreads();
  sm = reds[0] + reds[1] + reds[2] + reds[3];
  float lse = mx + logf(sm);
  float4 r = make_float4(v.x - lse, v.y - lse, v.z - lse, v.w - lse);
  *(float4*)(out + b * 1024 + 4 * t) = r;
}

extern "C" void kernel_launch(void* const* d_in, const int* in_sizes, int n_in,
                              void* d_out, int out_size, void* d_ws, size_t ws_size,
                              hipStream_t stream) {
  const float* x   = (const float*)d_in[0];
  const float* adj = (const float*)d_in[1];
  const float* W   = (const float*)d_in[2];
  const float* a   = (const float*)d_in[3];
  const float* fcw = (const float*)d_in[4];
  const float* fcb = (const float*)d_in[5];
  float* out = (float*)d_out;

  char* ws = (char*)d_ws;
  float* Whp = (float*)(ws);                // 4 * 7,340,032 = 29,360,128 B
  float* dp  = (float*)(ws + 29360128);     // 4*128*28*4 = 57,344 B
  float* hp  = (float*)(ws + 29417472);     // 7,340,032 B
  float* oap = (float*)(ws + 36757504);     // 64 * 32 * 1024 * 4 = 8,388,608 B

  k1_wh<<<512, 256, 0, stream>>>(x, W, a, Whp, dp);
  k3_atthp<<<512, 128, 0, stream>>>(Whp, dp, adj, hp);
  k4_fc<<<1024, 256, 0, stream>>>(hp, fcw, oap);
  k5_lsm<<<32, 256, 0, stream>>>(oap, fcb, out);
}